// Round 3
// baseline (217.493 us; speedup 1.0000x reference)
//
#include <hip/hip_runtime.h>

#define D  64    // feature dim (fixed by problem)
#define JB 256   // columns (x2 rows) per block = 4 waves * 64 lanes
#define IB 128   // x1 rows per block (min-trick kernel)

typedef _Float16 h2 __attribute__((ext_vector_type(2)));

#define LOG2E_OVER_64 0.022542140772245335f
#define LOG2E_OVER_32 0.04508428154449067f

// ---- pre-kernel 1: convert x1,x2 fp32 -> fp16 (RTN) into workspace ----
__global__ void cvt_f32_to_f16(const float* __restrict__ x1,
                               const float* __restrict__ x2,
                               _Float16* __restrict__ x1h,
                               _Float16* __restrict__ x2h,
                               int n1, int n2)  // float counts
{
    int idx = blockIdx.x * blockDim.x + threadIdx.x;  // one idx = 4 floats
    int t1 = n1 / 4, tt = (n1 + n2) / 4;
    if (idx < t1) {
        float4 v = reinterpret_cast<const float4*>(x1)[idx];
        h2 lo = { (_Float16)v.x, (_Float16)v.y };
        h2 hi = { (_Float16)v.z, (_Float16)v.w };
        uint2 u = { __builtin_bit_cast(unsigned, lo), __builtin_bit_cast(unsigned, hi) };
        reinterpret_cast<uint2*>(x1h)[idx] = u;
    } else if (idx < tt) {
        int k = idx - t1;
        float4 v = reinterpret_cast<const float4*>(x2)[k];
        h2 lo = { (_Float16)v.x, (_Float16)v.y };
        h2 hi = { (_Float16)v.z, (_Float16)v.w };
        uint2 u = { __builtin_bit_cast(unsigned, lo), __builtin_bit_cast(unsigned, hi) };
        reinterpret_cast<uint2*>(x2h)[k] = u;
    }
}

// ---- pre-kernel 2: per-row sum of fp16 values, scaled by log2e/64 ----
// f[r] = (sum_k xh[r,k]) * log2e/64, computed in fp32 from the CONVERTED
// values (so conversion error profile matches the main-loop terms).
__global__ void rowsum_f16(const _Float16* __restrict__ xh,
                           float* __restrict__ f, int nrows)
{
    int r = blockIdx.x * blockDim.x + threadIdx.x;
    if (r >= nrows) return;
    const uint4* p = reinterpret_cast<const uint4*>(xh + (size_t)r * D);
    float s = 0.f;
#pragma unroll
    for (int c = 0; c < 8; ++c) {
        uint4 v = p[c];
        h2 a = __builtin_bit_cast(h2, v.x); s += (float)a.x + (float)a.y;
        h2 b = __builtin_bit_cast(h2, v.y); s += (float)b.x + (float)b.y;
        h2 e = __builtin_bit_cast(h2, v.z); s += (float)e.x + (float)e.y;
        h2 g = __builtin_bit_cast(h2, v.w); s += (float)g.x + (float)g.y;
    }
    f[r] = s * LOG2E_OVER_64;
}

// ---- main kernel: min-trick L1, inline-asm packed-fp16 core ----
// S_ij = rsA_i + rsB_j - 2*sum_k min(a_ik, b_jk)
// out  = exp2( M*(log2e/32) - fA_i - fB_j ),  M = sum min (fp16 packed acc)
// Core: v_pk_min_f16 + v_pk_add_f16 = 1.0 VALU inst per dim, pinned by asm.
__global__ __launch_bounds__(256, 6) void laplace_min_kernel(
    const _Float16* __restrict__ x1h, const _Float16* __restrict__ x2h,
    const float* __restrict__ fA, const float* __restrict__ fB,
    float* __restrict__ out, int n, int m)
{
    const int j     = blockIdx.x * JB + threadIdx.x;
    const int ibase = blockIdx.y * IB;

    // Cache this lane's x2 row as 32 packed half2 words, pinned in VGPRs.
    unsigned bb[32];
    const uint4* b4 = reinterpret_cast<const uint4*>(x2h + (size_t)j * D);
#pragma unroll
    for (int c = 0; c < 8; ++c) {
        uint4 v = b4[c];
        bb[4*c+0] = v.x; bb[4*c+1] = v.y; bb[4*c+2] = v.z; bb[4*c+3] = v.w;
    }
#pragma unroll
    for (int q = 0; q < 32; ++q) asm volatile("" : "+v"(bb[q]));

    const float negfB = -fB[j];
    const float k32   = LOG2E_OVER_32;

    const uint4* a4   = reinterpret_cast<const uint4*>(x1h + (size_t)ibase * D);
    const float* pA   = fA + ibase;
    float*       orow = out + (size_t)ibase * m + j;

#pragma unroll 2
    for (int i = 0; i < IB; ++i) {
        unsigned acc0, acc1, acc2, acc3, t;
        // Group 0 initializes the accumulators (saves 4 movs + 4 adds).
        {
            uint4 av = a4[0];
            asm("v_pk_min_f16 %0, %1, %2" : "=v"(acc0) : "v"(av.x), "v"(bb[0]));
            asm("v_pk_min_f16 %0, %1, %2" : "=v"(acc1) : "v"(av.y), "v"(bb[1]));
            asm("v_pk_min_f16 %0, %1, %2" : "=v"(acc2) : "v"(av.z), "v"(bb[2]));
            asm("v_pk_min_f16 %0, %1, %2" : "=v"(acc3) : "v"(av.w), "v"(bb[3]));
        }
#pragma unroll
        for (int c = 1; c < 8; ++c) {
            uint4 av = a4[c];
            asm("v_pk_min_f16 %0, %1, %2" : "=v"(t) : "v"(av.x), "v"(bb[4*c+0]));
            asm("v_pk_add_f16 %0, %0, %1" : "+v"(acc0) : "v"(t));
            asm("v_pk_min_f16 %0, %1, %2" : "=v"(t) : "v"(av.y), "v"(bb[4*c+1]));
            asm("v_pk_add_f16 %0, %0, %1" : "+v"(acc1) : "v"(t));
            asm("v_pk_min_f16 %0, %1, %2" : "=v"(t) : "v"(av.z), "v"(bb[4*c+2]));
            asm("v_pk_add_f16 %0, %0, %1" : "+v"(acc2) : "v"(t));
            asm("v_pk_min_f16 %0, %1, %2" : "=v"(t) : "v"(av.w), "v"(bb[4*c+3]));
            asm("v_pk_add_f16 %0, %0, %1" : "+v"(acc3) : "v"(t));
        }
        asm("v_pk_add_f16 %0, %0, %1" : "+v"(acc0) : "v"(acc1));
        asm("v_pk_add_f16 %0, %0, %1" : "+v"(acc2) : "v"(acc3));
        asm("v_pk_add_f16 %0, %0, %1" : "+v"(acc0) : "v"(acc2));

        h2 r2 = __builtin_bit_cast(h2, acc0);
        float Mf  = (float)r2.x + (float)r2.y;
        float arg = fmaf(Mf, k32, negfB - pA[i]);
        orow[0] = __builtin_amdgcn_exp2f(arg);

        a4 += 8;
        orow += m;
    }
}

// ---- fallback (ws too small): fp32 kernel with pinned b ----
__global__ __launch_bounds__(256, 4) void laplace_f32_kernel(
    const float* __restrict__ x1, const float* __restrict__ x2,
    float* __restrict__ out, int n, int m)
{
    const int j     = blockIdx.x * JB + threadIdx.x;
    const int ibase = blockIdx.y * 256;

    float b[D];
    const float4* x2r = reinterpret_cast<const float4*>(x2 + (size_t)j * D);
#pragma unroll
    for (int q = 0; q < D / 4; ++q) {
        float4 v = x2r[q];
        b[4*q+0] = v.x; b[4*q+1] = v.y; b[4*q+2] = v.z; b[4*q+3] = v.w;
    }
#pragma unroll
    for (int q = 0; q < D; ++q) asm volatile("" : "+v"(b[q]));

    for (int i = ibase; i < ibase + 256; ++i) {
        const float4* a4 = reinterpret_cast<const float4*>(x1 + (size_t)i * D);
        float acc0 = 0.f, acc1 = 0.f, acc2 = 0.f, acc3 = 0.f;
#pragma unroll
        for (int q = 0; q < D / 4; ++q) {
            float4 av = a4[q];
            acc0 += fabsf(av.x - b[4*q+0]);
            acc1 += fabsf(av.y - b[4*q+1]);
            acc2 += fabsf(av.z - b[4*q+2]);
            acc3 += fabsf(av.w - b[4*q+3]);
        }
        float s = (acc0 + acc1) + (acc2 + acc3);
        out[(size_t)i * m + j] = __expf(s * -0.015625f);
    }
}

extern "C" void kernel_launch(void* const* d_in, const int* in_sizes, int n_in,
                              void* d_out, int out_size, void* d_ws, size_t ws_size,
                              hipStream_t stream)
{
    const float* x1 = (const float*)d_in[0];
    const float* x2 = (const float*)d_in[1];
    float* out = (float*)d_out;
    const int n = in_sizes[0] / D;   // 8192
    const int m = in_sizes[1] / D;   // 8192

    const size_t half_bytes = ((size_t)n + (size_t)m) * D * sizeof(_Float16);  // 2 MB
    const size_t need = half_bytes + ((size_t)n + (size_t)m) * sizeof(float);  // +64 KB
    if (ws_size >= need) {
        _Float16* x1h = (_Float16*)d_ws;
        _Float16* x2h = x1h + (size_t)n * D;
        float* fA = (float*)((char*)d_ws + half_bytes);
        float* fB = fA + n;

        const int total4 = (in_sizes[0] + in_sizes[1]) / 4;
        cvt_f32_to_f16<<<(total4 + 255) / 256, 256, 0, stream>>>(
            x1, x2, x1h, x2h, in_sizes[0], in_sizes[1]);
        rowsum_f16<<<(n + 255) / 256, 256, 0, stream>>>(x1h, fA, n);
        rowsum_f16<<<(m + 255) / 256, 256, 0, stream>>>(x2h, fB, m);

        dim3 grid(m / JB, n / IB);   // 32 x 64
        laplace_min_kernel<<<grid, 256, 0, stream>>>(x1h, x2h, fA, fB, out, n, m);
    } else {
        dim3 grid(m / JB, n / 256); // 32 x 32
        laplace_f32_kernel<<<grid, 256, 0, stream>>>(x1, x2, out, n, m);
    }
}

// Round 4
// 166.035 us; speedup vs baseline: 1.3099x; 1.3099x over previous
//
#include <hip/hip_runtime.h>

#define D  64    // feature dim (fixed by problem)
#define JB 256   // columns (x2 rows) per block = 4 waves * 64 lanes
#define IB 128   // x1 rows per block

typedef _Float16 h2  __attribute__((ext_vector_type(2)));
typedef int      si16 __attribute__((ext_vector_type(16)));

#define LOG2E_OVER_64 0.022542140772245335f
#define LOG2E_OVER_32 0.04508428154449067f

// ---- pre-kernel 1: convert x1,x2 fp32 -> fp16 (RTN) into workspace ----
__global__ void cvt_f32_to_f16(const float* __restrict__ x1,
                               const float* __restrict__ x2,
                               _Float16* __restrict__ x1h,
                               _Float16* __restrict__ x2h,
                               int n1, int n2)  // float counts
{
    int idx = blockIdx.x * blockDim.x + threadIdx.x;  // one idx = 4 floats
    int t1 = n1 / 4, tt = (n1 + n2) / 4;
    if (idx < t1) {
        float4 v = reinterpret_cast<const float4*>(x1)[idx];
        h2 lo = { (_Float16)v.x, (_Float16)v.y };
        h2 hi = { (_Float16)v.z, (_Float16)v.w };
        uint2 u = { __builtin_bit_cast(unsigned, lo), __builtin_bit_cast(unsigned, hi) };
        reinterpret_cast<uint2*>(x1h)[idx] = u;
    } else if (idx < tt) {
        int k = idx - t1;
        float4 v = reinterpret_cast<const float4*>(x2)[k];
        h2 lo = { (_Float16)v.x, (_Float16)v.y };
        h2 hi = { (_Float16)v.z, (_Float16)v.w };
        uint2 u = { __builtin_bit_cast(unsigned, lo), __builtin_bit_cast(unsigned, hi) };
        reinterpret_cast<uint2*>(x2h)[k] = u;
    }
}

// ---- pre-kernel 2: per-row sum of fp16 values, scaled by log2e/64 ----
__global__ void rowsum_f16(const _Float16* __restrict__ xh,
                           float* __restrict__ f, int nrows)
{
    int r = blockIdx.x * blockDim.x + threadIdx.x;
    if (r >= nrows) return;
    const uint4* p = reinterpret_cast<const uint4*>(xh + (size_t)r * D);
    float s = 0.f;
#pragma unroll
    for (int c = 0; c < 8; ++c) {
        uint4 v = p[c];
        h2 a = __builtin_bit_cast(h2, v.x); s += (float)a.x + (float)a.y;
        h2 b = __builtin_bit_cast(h2, v.y); s += (float)b.x + (float)b.y;
        h2 e = __builtin_bit_cast(h2, v.z); s += (float)e.x + (float)e.y;
        h2 g = __builtin_bit_cast(h2, v.w); s += (float)g.x + (float)g.y;
    }
    f[r] = s * LOG2E_OVER_64;
}

// ---- main kernel: min-trick L1; x1 row in SGPRs (s_load_dwordx16, 1-row
// prefetch), x2 row pinned in VGPRs; core = v_pk_min_f16(v,s,v)+v_pk_add_f16.
// S_ij = rsA_i + rsB_j - 2*sum_k min(a,b);  out = exp2(M*log2e/32 - fA - fB).
__global__ __launch_bounds__(256, 8) void laplace_sgpr_kernel(
    const _Float16* __restrict__ x1h, const _Float16* __restrict__ x2h,
    const float* __restrict__ fA, const float* __restrict__ fB,
    float* __restrict__ out, int n, int m)
{
    const int tid   = threadIdx.x;
    const int j     = blockIdx.x * JB + tid;
    const int ibase = blockIdx.y * IB;

    // Cache this lane's x2 row as 32 packed half2 words, pinned in VGPRs.
    unsigned bb[32];
    const uint4* b4 = reinterpret_cast<const uint4*>(x2h + (size_t)j * D);
#pragma unroll
    for (int c = 0; c < 8; ++c) {
        uint4 v = b4[c];
        bb[4*c+0] = v.x; bb[4*c+1] = v.y; bb[4*c+2] = v.z; bb[4*c+3] = v.w;
    }
#pragma unroll
    for (int q = 0; q < 32; ++q) asm volatile("" : "+v"(bb[q]));

    const float negfB = -fB[j];
    const float k32   = LOG2E_OVER_32;

    // Uniform scalar pointers.
    const _Float16* ap = x1h + (size_t)ibase * D;  // row pointer (128 B rows)
    const float*    fp = fA + ibase;
    float* obase = out + (size_t)ibase * m + (size_t)blockIdx.x * JB; // uniform

    si16 A0, A1, B0, B1;
    float faA, faB;

    // Preload row 0 (+ its fA) into buffer A.
    asm volatile("s_load_dwordx16 %0, %3, 0x0\n\t"
                 "s_load_dwordx16 %1, %3, 0x40\n\t"
                 "s_load_dword    %2, %4, 0x0"
                 : "=s"(A0), "=s"(A1), "=s"(faA)
                 : "s"(ap), "s"(fp));
    ap += D; fp += 1;

#define ROW_BODY(C0, C1, FC, N0, N1, FN)                                      \
    {                                                                         \
        /* row data ready; tie consumed buffers so core can't hoist */        \
        asm volatile("s_waitcnt lgkmcnt(0)"                                   \
                     : "+s"(C0), "+s"(C1), "+s"(FC));                         \
        /* prefetch next row into the other buffer */                         \
        asm volatile("s_load_dwordx16 %0, %3, 0x0\n\t"                        \
                     "s_load_dwordx16 %1, %3, 0x40\n\t"                       \
                     "s_load_dword    %2, %4, 0x0"                            \
                     : "=s"(N0), "=s"(N1), "=s"(FN)                           \
                     : "s"(ap), "s"(fp));                                     \
        ap += D; fp += 1;                                                     \
        unsigned acc0, acc1, acc2, acc3, t;                                   \
        asm("v_pk_min_f16 %0, %1, %2" : "=v"(acc0) : "s"(C0[0]), "v"(bb[0])); \
        asm("v_pk_min_f16 %0, %1, %2" : "=v"(acc1) : "s"(C0[1]), "v"(bb[1])); \
        asm("v_pk_min_f16 %0, %1, %2" : "=v"(acc2) : "s"(C0[2]), "v"(bb[2])); \
        asm("v_pk_min_f16 %0, %1, %2" : "=v"(acc3) : "s"(C0[3]), "v"(bb[3])); \
        _Pragma("unroll")                                                     \
        for (int w = 4; w < 16; ++w) {                                        \
            asm("v_pk_min_f16 %0, %1, %2" : "=v"(t) : "s"(C0[w]), "v"(bb[w]));\
            if ((w & 3) == 0) asm("v_pk_add_f16 %0, %0, %1" : "+v"(acc0) : "v"(t)); \
            if ((w & 3) == 1) asm("v_pk_add_f16 %0, %0, %1" : "+v"(acc1) : "v"(t)); \
            if ((w & 3) == 2) asm("v_pk_add_f16 %0, %0, %1" : "+v"(acc2) : "v"(t)); \
            if ((w & 3) == 3) asm("v_pk_add_f16 %0, %0, %1" : "+v"(acc3) : "v"(t)); \
        }                                                                     \
        _Pragma("unroll")                                                     \
        for (int w = 0; w < 16; ++w) {                                        \
            asm("v_pk_min_f16 %0, %1, %2" : "=v"(t) : "s"(C1[w]), "v"(bb[16+w])); \
            if ((w & 3) == 0) asm("v_pk_add_f16 %0, %0, %1" : "+v"(acc0) : "v"(t)); \
            if ((w & 3) == 1) asm("v_pk_add_f16 %0, %0, %1" : "+v"(acc1) : "v"(t)); \
            if ((w & 3) == 2) asm("v_pk_add_f16 %0, %0, %1" : "+v"(acc2) : "v"(t)); \
            if ((w & 3) == 3) asm("v_pk_add_f16 %0, %0, %1" : "+v"(acc3) : "v"(t)); \
        }                                                                     \
        asm("v_pk_add_f16 %0, %0, %1" : "+v"(acc0) : "v"(acc1));              \
        asm("v_pk_add_f16 %0, %0, %1" : "+v"(acc2) : "v"(acc3));              \
        asm("v_pk_add_f16 %0, %0, %1" : "+v"(acc0) : "v"(acc2));              \
        h2 r2 = __builtin_bit_cast(h2, acc0);                                 \
        float Mf  = (float)r2.x + (float)r2.y;                                \
        float cc  = negfB - FC;                                               \
        float arg = fmaf(Mf, k32, cc);                                        \
        obase[tid] = __builtin_amdgcn_exp2f(arg);                             \
        obase += m;                                                           \
    }

    for (int ii = 0; ii < IB; ii += 2) {
        ROW_BODY(A0, A1, faA, B0, B1, faB)
        ROW_BODY(B0, B1, faB, A0, A1, faA)
    }
#undef ROW_BODY
}

// ---- fallback (ws too small): fp32 kernel with pinned b ----
__global__ __launch_bounds__(256, 4) void laplace_f32_kernel(
    const float* __restrict__ x1, const float* __restrict__ x2,
    float* __restrict__ out, int n, int m)
{
    const int j     = blockIdx.x * JB + threadIdx.x;
    const int ibase = blockIdx.y * 256;

    float b[D];
    const float4* x2r = reinterpret_cast<const float4*>(x2 + (size_t)j * D);
#pragma unroll
    for (int q = 0; q < D / 4; ++q) {
        float4 v = x2r[q];
        b[4*q+0] = v.x; b[4*q+1] = v.y; b[4*q+2] = v.z; b[4*q+3] = v.w;
    }
#pragma unroll
    for (int q = 0; q < D; ++q) asm volatile("" : "+v"(b[q]));

    for (int i = ibase; i < ibase + 256; ++i) {
        const float4* a4 = reinterpret_cast<const float4*>(x1 + (size_t)i * D);
        float acc0 = 0.f, acc1 = 0.f, acc2 = 0.f, acc3 = 0.f;
#pragma unroll
        for (int q = 0; q < D / 4; ++q) {
            float4 av = a4[q];
            acc0 += fabsf(av.x - b[4*q+0]);
            acc1 += fabsf(av.y - b[4*q+1]);
            acc2 += fabsf(av.z - b[4*q+2]);
            acc3 += fabsf(av.w - b[4*q+3]);
        }
        float s = (acc0 + acc1) + (acc2 + acc3);
        out[(size_t)i * m + j] = __expf(s * -0.015625f);
    }
}

extern "C" void kernel_launch(void* const* d_in, const int* in_sizes, int n_in,
                              void* d_out, int out_size, void* d_ws, size_t ws_size,
                              hipStream_t stream)
{
    const float* x1 = (const float*)d_in[0];
    const float* x2 = (const float*)d_in[1];
    float* out = (float*)d_out;
    const int n = in_sizes[0] / D;   // 8192
    const int m = in_sizes[1] / D;   // 8192

    const size_t half_bytes = ((size_t)n + (size_t)m) * D * sizeof(_Float16);  // 2 MB
    const size_t need = half_bytes + ((size_t)n + (size_t)m) * sizeof(float);  // +64 KB
    if (ws_size >= need) {
        _Float16* x1h = (_Float16*)d_ws;
        _Float16* x2h = x1h + (size_t)n * D;
        float* fA = (float*)((char*)d_ws + half_bytes);
        float* fB = fA + n;

        const int total4 = (in_sizes[0] + in_sizes[1]) / 4;
        cvt_f32_to_f16<<<(total4 + 255) / 256, 256, 0, stream>>>(
            x1, x2, x1h, x2h, in_sizes[0], in_sizes[1]);
        rowsum_f16<<<(n + 255) / 256, 256, 0, stream>>>(x1h, fA, n);
        rowsum_f16<<<(m + 255) / 256, 256, 0, stream>>>(x2h, fB, m);

        dim3 grid(m / JB, n / IB);   // 32 x 64 = 2048 blocks = 8/CU
        laplace_sgpr_kernel<<<grid, 256, 0, stream>>>(x1h, x2h, fA, fB, out, n, m);
    } else {
        dim3 grid(m / JB, n / 256); // 32 x 32
        laplace_f32_kernel<<<grid, 256, 0, stream>>>(x1, x2, out, n, m);
    }
}